// Round 2
// baseline (219.978 us; speedup 1.0000x reference)
//
#include <hip/hip_runtime.h>
#include <cstdint>
#include <cstddef>

#define B_N   16
#define G_N   128
#define FD_N  8192
#define KSPLIT 16
#define KC    512        // FD_N / KSPLIT
#define BK    64
#define NSTAGE 8         // KC / BK

typedef unsigned short u16;
typedef u16  u16x8 __attribute__((ext_vector_type(8)));
typedef __bf16 bf16x8 __attribute__((ext_vector_type(8)));
typedef float f32x16 __attribute__((ext_vector_type(16)));

// ---- ws layout (float offsets). Everything written before read; NO zero-init needed.
#define QSUM_P   0        // [kch][b][row] 16*16*128
#define QSSQ_P   32768
#define KSUM_P   65536
#define KSSQ_P   98304
#define NSSQ_P   131072
#define SM_ROW   163840   // [b][row]
#define CE_ROW   165888
#define S_OFF    167936   // [b][128][128] fp32 normalized S
// u16 region: partials [b2=32][row 128][kch 16][col 128] bf16 (16.8 MB, same size/offset)
#define PART_OFF_F 430080

__device__ __forceinline__ u16 f2bf(float f) {
    uint32_t u = __float_as_uint(f);
    u += 0x7FFFu + ((u >> 16) & 1u);      // RNE
    return (u16)(u >> 16);
}

#define LGKM0_BAR() do { asm volatile("s_waitcnt lgkmcnt(0)" ::: "memory"); \
                         __builtin_amdgcn_s_barrier(); } while (0)

// ================= K1: bf16 GEMM, tile 128 x 256 (cols 0-127 = q.kT, 128-255 = q.nT) =========
// grid = 16b * 16kch = 256 blocks x 512 thr = EXACTLY 1 block/CU, zero tail.
// Memory-pattern redesign: each staged row is read as 256-B contiguous bursts (one dwordx4
// instruction covers 4 rows x 256B) instead of 16 temporally-scattered 128-B visits -> DRAM
// row-activate amortization. q read ONCE (k/n halves merged): request 256->192 MB.
// Register-staged (12 dwordx4/wave in flight across the whole MFMA phase), bf16 LDS ping-pong
// (96 KB), XOR-swizzled 8B units so frag ds_read_b128 is ~4-way max. Stats computed at stage
// time (each element exactly once, by its stager).
__global__ __launch_bounds__(512, 2)
void k_gemm(const float* __restrict__ q, const float* __restrict__ kM,
            const float* __restrict__ nM, float* __restrict__ ws)
{
    __shared__ __align__(16) u16 smem[2 * 24576];   // [buf][A 8192 | B 16384] u16 = 96 KB

    const int tid = threadIdx.x;
    const int blk = blockIdx.x;       // b*16 + kch
    const int b   = blk >> 4;
    const int kch = blk & 15;

    const int lane  = tid & 63;
    const int wv    = tid >> 6;       // 8 waves
    const int wm    = wv >> 2;        // 0..1 -> 64-row block
    const int wn    = wv & 3;         // 0..3 -> 64-col block
    const int khalf = lane >> 5;
    const int lrow  = lane & 31;
    const int g     = lane >> 4;      // 0..3  (row-within-quad for staging)
    const int cc    = lane & 15;      // 0..15 (16B slot within 256B burst)

    const size_t mat_off = (size_t)b * (G_N * FD_N) + (size_t)kch * KC;
    const float* Ap = q + mat_off;
    const float* Bw = (wv < 4 ? kM : nM) + mat_off;   // waves 0-3 stage k, 4-7 stage n

    // staged rows: A rows wv*16 + i*4 + g (i 0..3); B rows wn*32 + i*4 + g (i 0..7)
    float4 La[4], Lb[8];
    float sA_[4] = {0,0,0,0}, qA_[4] = {0,0,0,0};
    float sB_[8] = {0,0,0,0,0,0,0,0}, qB_[8] = {0,0,0,0,0,0,0,0};

    f32x16 acc[2][2];
    #pragma unroll
    for (int m = 0; m < 2; ++m)
      #pragma unroll
      for (int n = 0; n < 2; ++n)
        #pragma unroll
        for (int e = 0; e < 16; ++e) acc[m][n][e] = 0.f;

    // one load instruction = 4 rows x 256B contiguous (lane: row += g, bytes cc*16)
#define ISSUE(S) do {                                                          \
        const size_t ko_ = (size_t)((S)*BK + cc*4);                            \
        _Pragma("unroll")                                                      \
        for (int i = 0; i < 4; ++i)                                            \
            La[i] = *(const float4*)(Ap + (size_t)(wv*16 + i*4 + g)*FD_N + ko_); \
        _Pragma("unroll")                                                      \
        for (int i = 0; i < 8; ++i)                                            \
            Lb[i] = *(const float4*)(Bw + (size_t)(wn*32 + i*4 + g)*FD_N + ko_); \
    } while (0)

    // LDS row = 64 bf16 = 128B = sixteen 8B units; unit index swizzled: cc ^ ((row&7)<<1).
    // Frag read (16B = two adjacent swizzled 8B units) lands at ((kc*2+khalf)^(row&7))<<3.
#define CVTWRITE(BUF) do {                                                     \
        u16* dA_ = smem + (BUF)*24576;                                         \
        u16* dB_ = dA_ + 8192;                                                 \
        _Pragma("unroll")                                                      \
        for (int i = 0; i < 4; ++i) {                                          \
            const int r_ = wv*16 + i*4 + g;                                    \
            float4 v = La[i];                                                  \
            sA_[i] += (v.x + v.y) + (v.z + v.w);                               \
            qA_[i] += v.x*v.x + v.y*v.y + v.z*v.z + v.w*v.w;                   \
            uint2 p;                                                           \
            p.x = (uint32_t)f2bf(v.x) | ((uint32_t)f2bf(v.y) << 16);           \
            p.y = (uint32_t)f2bf(v.z) | ((uint32_t)f2bf(v.w) << 16);           \
            *(uint2*)(dA_ + r_*64 + ((cc ^ ((r_&7)<<1)) << 2)) = p;            \
        }                                                                      \
        _Pragma("unroll")                                                      \
        for (int i = 0; i < 8; ++i) {                                          \
            const int r_  = wn*32 + i*4 + g;                                   \
            const int rl_ = r_ + (wv < 4 ? 0 : 128);                           \
            float4 v = Lb[i];                                                  \
            sB_[i] += (v.x + v.y) + (v.z + v.w);                               \
            qB_[i] += v.x*v.x + v.y*v.y + v.z*v.z + v.w*v.w;                   \
            uint2 p;                                                           \
            p.x = (uint32_t)f2bf(v.x) | ((uint32_t)f2bf(v.y) << 16);           \
            p.y = (uint32_t)f2bf(v.z) | ((uint32_t)f2bf(v.w) << 16);           \
            *(uint2*)(dB_ + rl_*64 + ((cc ^ ((rl_&7)<<1)) << 2)) = p;          \
        }                                                                      \
    } while (0)

#define FRAG(DP, R, KCH)                                                       \
    __builtin_bit_cast(bf16x8, *(const u16x8*)((DP) + (R)*64 +                 \
        ((((KCH)*2 + khalf) ^ ((R)&7)) << 3)))

#define COMPUTE(BUF) do {                                                      \
        const u16* dA_ = smem + (BUF)*24576;                                   \
        const u16* dB_ = dA_ + 8192;                                           \
        __builtin_amdgcn_s_setprio(1);                                         \
        _Pragma("unroll")                                                      \
        for (int kc = 0; kc < 4; ++kc) {                                       \
            bf16x8 a0_ = FRAG(dA_, wm*64 +      lrow, kc);                     \
            bf16x8 a1_ = FRAG(dA_, wm*64 + 32 + lrow, kc);                     \
            bf16x8 b0_ = FRAG(dB_, wn*64 +      lrow, kc);                     \
            bf16x8 b1_ = FRAG(dB_, wn*64 + 32 + lrow, kc);                     \
            acc[0][0] = __builtin_amdgcn_mfma_f32_32x32x16_bf16(a0_, b0_, acc[0][0], 0,0,0); \
            acc[0][1] = __builtin_amdgcn_mfma_f32_32x32x16_bf16(a0_, b1_, acc[0][1], 0,0,0); \
            acc[1][0] = __builtin_amdgcn_mfma_f32_32x32x16_bf16(a1_, b0_, acc[1][0], 0,0,0); \
            acc[1][1] = __builtin_amdgcn_mfma_f32_32x32x16_bf16(a1_, b1_, acc[1][1], 0,0,0); \
        }                                                                      \
        __builtin_amdgcn_s_setprio(0);                                         \
    } while (0)

    // prologue: stage 0 (exposed fill)
    ISSUE(0);
    CVTWRITE(0);
    LGKM0_BAR();

    // steady state: next stage's loads fly across the whole MFMA phase (T14).
    for (int s = 0; s < NSTAGE; ++s) {
        if (s + 1 < NSTAGE) ISSUE(s + 1);
        COMPUTE(s & 1);
        if (s + 1 < NSTAGE) {
            LGKM0_BAR();                   // all reads of buf (s+1)&1 finished 2 barriers ago
            CVTWRITE((s + 1) & 1);
            LGKM0_BAR();
        }
    }

    // ---- C write: layout [b2][row][kch][col] bf16; C/D map col=lane&31,
    // row=(reg&3)+8*(reg>>2)+4*khalf
    u16* part = (u16*)(ws + PART_OFF_F);
    #pragma unroll
    for (int m = 0; m < 2; ++m)
      #pragma unroll
      for (int n = 0; n < 2; ++n) {
        const int colg = wn*64 + n*32 + lrow;     // 0..255
        const int ho   = colg >> 7;               // 0: k-half, 1: n-half
        const int col  = colg & 127;
        u16* pb = part + (size_t)(b*2 + ho) * 262144;
        const int rbase = wm*64 + m*32 + 4*khalf;
        #pragma unroll
        for (int reg = 0; reg < 16; ++reg) {
            const int row = rbase + (reg & 3) + 8*(reg >> 2);
            pb[(row*16 + kch)*128 + col] = f2bf(acc[m][n][reg]);
        }
      }

    // ---- per-chunk row stats: reduce over the 16 lanes (cc) sharing each row
    #pragma unroll
    for (int i = 0; i < 4; ++i)
        #pragma unroll
        for (int msk = 8; msk >= 1; msk >>= 1) {
            sA_[i] += __shfl_xor(sA_[i], msk, 64);
            qA_[i] += __shfl_xor(qA_[i], msk, 64);
        }
    #pragma unroll
    for (int i = 0; i < 8; ++i)
        #pragma unroll
        for (int msk = 8; msk >= 1; msk >>= 1) {
            sB_[i] += __shfl_xor(sB_[i], msk, 64);
            qB_[i] += __shfl_xor(qB_[i], msk, 64);
        }
    if (cc == 0) {
        #pragma unroll
        for (int i = 0; i < 4; ++i) {
            const int o = kch*2048 + b*G_N + (wv*16 + i*4 + g);
            ws[QSUM_P + o] = sA_[i]; ws[QSSQ_P + o] = qA_[i];
        }
        #pragma unroll
        for (int i = 0; i < 8; ++i) {
            const int o = kch*2048 + b*G_N + (wn*32 + i*4 + g);
            if (wv < 4) { ws[KSUM_P + o] = sB_[i]; ws[KSSQ_P + o] = qB_[i]; }
            else        { ws[NSSQ_P + o] = qB_[i]; }
        }
    }
#undef ISSUE
#undef CVTWRITE
#undef FRAG
#undef COMPUTE
}

// ================= K2: reduce chunks + normalize + write S / sm-row / CE-expsum-row ==========
// grid = 16b * 2half * 8rowgroups = 256 blocks x 256 thr. Also zeroes out[0] for K3's atomics.
// Partials now [b2][row][kch][col]: the 16-chunk reduction walks each row's 4KB contiguously.
__global__ __launch_bounds__(256)
void k_red2(float* __restrict__ ws, float* __restrict__ out)
{
    const int blk  = blockIdx.x;
    const int b    = blk >> 4;
    const int half = (blk >> 3) & 1;
    const int rg   = blk & 7;
    const int t    = threadIdx.x;
    const int lr   = t >> 4;            // 0..15
    const int i    = rg*16 + lr;
    const int c8   = t & 15;            // 8 cols each
    __shared__ float nrm[128];          // 1/||k_j|| or 1/||n_j||
    __shared__ float invq_s[16];

    if (blk == 0 && t == 0) out[0] = 0.f;

    if (t < 128) {
        float ss = 0.f;
        const float* p = ws + (half ? NSSQ_P : KSSQ_P) + b*G_N + t;
        #pragma unroll
        for (int kc2 = 0; kc2 < KSPLIT; ++kc2) ss += p[kc2*2048];
        nrm[t] = 1.f / fmaxf(sqrtf(ss), 1e-12f);
    } else if (t < 144) {
        float ss = 0.f;
        const float* p = ws + QSSQ_P + b*G_N + rg*16 + (t - 128);
        #pragma unroll
        for (int kc2 = 0; kc2 < KSPLIT; ++kc2) ss += p[kc2*2048];
        invq_s[t-128] = 1.f / fmaxf(sqrtf(ss), 1e-12f);
    }
    __syncthreads();

    const u16* part = (const u16*)(ws + PART_OFF_F) + (size_t)(b*2 + half) * 262144;
    float s[8] = {0,0,0,0,0,0,0,0};
    #pragma unroll
    for (int kc2 = 0; kc2 < KSPLIT; ++kc2) {
        u16x8 h = *(const u16x8*)(part + (size_t)(i*16 + kc2)*128 + c8*8);
        #pragma unroll
        for (int e = 0; e < 8; ++e)
            s[e] += __uint_as_float(((uint32_t)h[e]) << 16);
    }
    const float iq = invq_s[lr];
    if (half == 0) {
        float smacc = 0.f;
        float S8[8];
        #pragma unroll
        for (int e = 0; e < 8; ++e) {
            int j = c8*8 + e;
            S8[e] = s[e] * iq * nrm[j];
            float d = S8[e] - (j == i ? 1.f : 0.f);
            smacc += d*d;
        }
        float* Sp = ws + S_OFF + (size_t)b*16384 + i*G_N + c8*8;
        float4 w0 = {S8[0],S8[1],S8[2],S8[3]};
        float4 w1 = {S8[4],S8[5],S8[6],S8[7]};
        *(float4*)Sp = w0; *(float4*)(Sp+4) = w1;
        #pragma unroll
        for (int m = 8; m >= 1; m >>= 1) smacc += __shfl_xor(smacc, m, 64);
        if (c8 == 0) ws[SM_ROW + b*G_N + i] = smacc;
    } else {
        float eacc = 0.f;
        #pragma unroll
        for (int e = 0; e < 8; ++e)
            eacc += __expf(5.f * s[e] * iq * nrm[c8*8+e]);
        #pragma unroll
        for (int m = 8; m >= 1; m >>= 1) eacc += __shfl_xor(eacc, m, 64);
        if (c8 == 0) ws[CE_ROW + b*G_N + i] = eacc;
    }
}

// ================= K3: tri/cyc/ce + weighted combine, atomic into out =================
// grid = 16b * 8rowgroups = 128 blocks x 256 thr. out[0] zeroed by K2 (stream-ordered).
__global__ __launch_bounds__(256)
void k_epi(float* __restrict__ ws, float* __restrict__ out)
{
    const int blk = blockIdx.x;
    const int b   = blk >> 3;
    const int i0  = (blk & 7) * 16;
    const int t   = threadIdx.x;
    __shared__ float sqv[128], skv[128], ddq[128], ddk[128];
    __shared__ float rbuf[4];
    const float c0 = (float)FD_N * 1e-6f * 1e-6f;

    const float* S = ws + S_OFF + (size_t)b * 16384;
    if (t < 128) {
        float qs=0, qq=0, ks=0, kq=0;
        #pragma unroll
        for (int kc2 = 0; kc2 < KSPLIT; ++kc2) {
            int o = kc2*2048 + b*G_N + t;
            qs += ws[QSUM_P + o]; qq += ws[QSSQ_P + o];
            ks += ws[KSUM_P + o]; kq += ws[KSSQ_P + o];
        }
        float iq = 1.f/fmaxf(sqrtf(qq),1e-12f);
        float ik = 1.f/fmaxf(sqrtf(kq),1e-12f);
        float sq = qs*iq, sk = ks*ik;
        sqv[t]=sq; skv[t]=sk;
        float Stt = S[t*G_N + t];
        ddq[t] = sqrtf(fmaxf(2.f - 2.f*Stt + 2e-6f*(sq-sk) + c0, 0.f));
        ddk[t] = sqrtf(fmaxf(2.f - 2.f*Stt + 2e-6f*(sk-sq) + c0, 0.f));
    }
    __syncthreads();

    float tri=0.f, cyc=0.f, ce=0.f, sm=0.f;
    #pragma unroll
    for (int p = 0; p < 8; ++p) {
        int idx = p*256 + t;
        int i = i0 + (idx >> 7), j = idx & 127;
        if (i != j) {
            float S_ij = S[i*G_N + j];
            float dqk = sqrtf(fmaxf(2.f - 2.f*S_ij + 2e-6f*(sqv[i]-skv[j]) + c0, 0.f));
            tri += fmaxf(ddq[i] - dqk + 1.f, 0.f);
            float dkq = sqrtf(fmaxf(2.f - 2.f*S_ij + 2e-6f*(skv[j]-sqv[i]) + c0, 0.f));
            tri += fmaxf(ddk[j] - dkq + 1.f, 0.f);
            cyc += fabsf(S_ij - S[j*G_N + i]);
        }
    }
    if (t < 16) {
        int r = i0 + t;
        float lp = 5.f * S[r*G_N + r];
        ce = __logf(ws[CE_ROW + b*G_N + r] + __expf(lp)) - lp;
        sm = ws[SM_ROW + b*G_N + r];
    }
    float contrib = sm * (1.f/16384.f) + cyc * (1.f/16256.f) + ce * (1.f/16384.f)
                  + (float)(B_N - b) * tri * (1.f/32512.f);
    #pragma unroll
    for (int m = 32; m >= 1; m >>= 1) contrib += __shfl_xor(contrib, m, 64);
    if ((t & 63) == 0) rbuf[t >> 6] = contrib;
    __syncthreads();
    if (t == 0) atomicAdd(out, rbuf[0] + rbuf[1] + rbuf[2] + rbuf[3]);
}

extern "C" void kernel_launch(void* const* d_in, const int* in_sizes, int n_in,
                              void* d_out, int out_size, void* d_ws, size_t ws_size,
                              hipStream_t stream)
{
    const float* q  = (const float*)d_in[0];
    const float* kM = (const float*)d_in[1];
    const float* nM = (const float*)d_in[2];
    float* ws  = (float*)d_ws;
    float* out = (float*)d_out;

    k_gemm<<<B_N * KSPLIT, 512, 0, stream>>>(q, kM, nM, ws);
    k_red2<<<256, 256, 0, stream>>>(ws, out);
    k_epi<<<128, 256, 0, stream>>>(ws, out);
}